// Round 12
// baseline (231.471 us; speedup 1.0000x reference)
//
#include <hip/hip_runtime.h>

#define NN 100000      // nodes
#define NE 1600000     // edges (without self loops)
#define NF 11          // input features
#define HID 128
#define NG 4096        // graphs

#define BSH 7
#define BNODES 128     // nodes per bucket = 1<<BSH
#define NBK 782        // ceil(NN/BNODES)
#define CAP 3072       // staging capacity per bucket (avg 2046)
#define EPB 4096       // edges per k_bucket block
#define NBB 391        // ceil(NE/EPB)

typedef short bf16x8 __attribute__((ext_vector_type(8)));
typedef float f32x4 __attribute__((ext_vector_type(4)));

// ---- bf16 pack/unpack helpers (RNE, no-NaN data) ----
__device__ __forceinline__ unsigned short f2bf(float f) {
    unsigned u = __float_as_uint(f);
    return (unsigned short)((u + 0x7FFFu + ((u >> 16) & 1u)) >> 16);
}
__device__ __forceinline__ unsigned packbf(float a, float b) {
    return (unsigned)f2bf(a) | ((unsigned)f2bf(b) << 16);
}
__device__ __forceinline__ float bflo(unsigned v) { return __uint_as_float(v << 16); }
__device__ __forceinline__ float bfhi(unsigned v) { return __uint_as_float(v & 0xFFFF0000u); }
__device__ __forceinline__ bf16x8 as_bf(uint4 u) { union { uint4 a; bf16x8 b; } v; v.a = u; return v.b; }

// ---- misc fused: zero bcur, pack W2 -> w2t, graph bounds, startp[NN]=NE ----
__global__ __launch_bounds__(256) void k_misc(int* __restrict__ bcur,
                                              const float* __restrict__ W2, unsigned* __restrict__ w2t,
                                              const int* __restrict__ batch, int* __restrict__ gs,
                                              int* __restrict__ startp) {
    int i = blockIdx.x * 256 + threadIdx.x;
    if (i < NBK) bcur[i] = 0;
    if (i < HID * 64) {   // 8192
        int col = i >> 6, kw = i & 63;
        w2t[col * 64 + kw] = packbf(W2[(2 * kw) * HID + col], W2[(2 * kw + 1) * HID + col]);
    }
    if (i <= NG) {
        int lo = 0, hi = NN;
        while (lo < hi) {
            int mid = (lo + hi) >> 1;
            if (batch[mid] < i) lo = mid + 1; else hi = mid;
        }
        gs[i] = lo;
    }
    if (i == 0) startp[NN] = NE;
}

// ---- pass 1: bucket edges by col>>7 into staging (workgroup multisplit) ----
__global__ __launch_bounds__(256) void k_bucket(const int* __restrict__ row, const int* __restrict__ col,
                                                int* __restrict__ bcur, int* __restrict__ staging) {
    __shared__ int cnt[NBK];
    __shared__ int loc[NBK];
    const int tid = threadIdx.x;
    const int e0 = blockIdx.x * EPB;
    for (int i = tid; i < NBK; i += 256) { cnt[i] = 0; loc[i] = 0; }
    __syncthreads();
    int rb[16]; unsigned pay[16];
#pragma unroll
    for (int j = 0; j < 16; ++j) {
        int e = e0 + j * 256 + tid;
        int c = (e < NE) ? __builtin_nontemporal_load(col + e) : -1;
        int r = (e < NE) ? __builtin_nontemporal_load(row + e) : 0;
        rb[j] = (c >= 0) ? (c >> BSH) : -1;
        pay[j] = (unsigned)r | ((unsigned)(c & (BNODES - 1)) << 17);
        if (rb[j] >= 0) atomicAdd(&cnt[rb[j]], 1);
    }
    __syncthreads();
    for (int b = tid; b < NBK; b += 256) {
        int c = cnt[b];
        cnt[b] = (c > 0) ? atomicAdd(&bcur[b], c) : 0;
    }
    __syncthreads();
#pragma unroll
    for (int j = 0; j < 16; ++j) {
        if (rb[j] >= 0) {
            int p = cnt[rb[j]] + atomicAdd(&loc[rb[j]], 1);
            staging[rb[j] * CAP + p] = (int)pay[j];
        }
    }
}

// ---- pass 2a: per-bucket histogram + local scan -> dis, startp(local), partial, xd8 ----
__global__ __launch_bounds__(256) void k_hist2s(const int* __restrict__ staging, const int* __restrict__ bcur,
                                                const float* __restrict__ x,
                                                float* __restrict__ dis, unsigned* __restrict__ xd8,
                                                int* __restrict__ startp, int* __restrict__ partial) {
    __shared__ int cnt[BNODES];
    __shared__ int sc[BNODES];
    const int b = blockIdx.x, tid = threadIdx.x;
    if (tid < BNODES) cnt[tid] = 0;
    __syncthreads();
    const int sz = bcur[b];
    const int base = b * CAP;
    for (int i = tid; i < sz; i += 256)
        atomicAdd(&cnt[((unsigned)staging[base + i]) >> 17], 1);
    __syncthreads();
    int v = (tid < BNODES) ? cnt[tid] : 0;
    if (tid < BNODES) sc[tid] = v;
    __syncthreads();
    for (int off = 1; off < BNODES; off <<= 1) {
        int u = (tid < BNODES && tid >= off) ? sc[tid - off] : 0;
        __syncthreads();
        if (tid < BNODES) sc[tid] += u;
        __syncthreads();
    }
    int n = b * BNODES + tid;
    if (tid < BNODES && n < NN) {
        startp[n] = sc[tid] - v;               // bucket-local exclusive
        float d = rsqrtf((float)(v + 1));
        dis[n] = d;
        // fused xd: xd8[n] = bf16(dis * x[n]) (6 packed pairs, row stride 8)
        const float* xr = x + (size_t)n * NF;
#pragma unroll
        for (int u = 0; u < 6; ++u) {
            float a = xr[2 * u] * d;
            float bq = (2 * u + 1 < NF) ? xr[2 * u + 1] * d : 0.f;
            xd8[n * 8 + u] = packbf(a, bq);
        }
    }
    if (tid == BNODES - 1) partial[b] = sc[BNODES - 1];   // bucket total
}

// ---- scan bucket totals (1 block, 1024 thr) ----
__global__ __launch_bounds__(1024) void k_scan2(int* __restrict__ partial) {
    __shared__ int sh[1024];
    int t = threadIdx.x;
    int v = (t < NBK) ? partial[t] : 0;
    sh[t] = v; __syncthreads();
    for (int off = 1; off < 1024; off <<= 1) {
        int u = (t >= off) ? sh[t - off] : 0; __syncthreads();
        sh[t] += u; __syncthreads();
    }
    if (t < NBK) partial[t] = sh[t] - v;       // exclusive bucket base
}

// ---- pass 2b: finalize startp and counting-sort into CSR ----
__global__ __launch_bounds__(256) void k_fillbs(const int* __restrict__ staging, const int* __restrict__ bcur,
                                                const int* __restrict__ partial,
                                                int* __restrict__ startp, int* __restrict__ csr) {
    __shared__ int cur[BNODES];
    const int b = blockIdx.x, tid = threadIdx.x;
    const int bb = partial[b];
    int n = b * BNODES + tid;
    if (tid < BNODES) {
        int sfin = 0;
        if (n < NN) {
            sfin = startp[n] + bb;
            startp[n] = sfin;
        }
        cur[tid] = sfin;
    }
    __syncthreads();
    const int sz = bcur[b];
    const int base = b * CAP;
    for (int i = tid; i < sz; i += 256) {
        unsigned p = (unsigned)__builtin_nontemporal_load(staging + base + i);
        int pos = atomicAdd(&cur[p >> 17], 1);
        csr[pos] = (int)(p & 0x1FFFF);
    }
}

// ---- gather layer 1 on 11-wide xd: one wave per node, 8 edge-groups x 8 feat-lanes ----
__global__ __launch_bounds__(256) void k_gat1(const unsigned* __restrict__ xd8,
                                              const int* __restrict__ startp,
                                              const int* __restrict__ csr,
                                              float2* __restrict__ aggf2) {
    const int node = blockIdx.x * 4 + (threadIdx.x >> 6);
    const int lane = threadIdx.x & 63;
    const int g = lane >> 3, f = lane & 7;    // 8 groups of 8 feat-lanes
    const int s = startp[node], e = startp[node + 1];
    float ax = 0.f, ay = 0.f;
    for (int i = s; i < e; i += 64) {
        int idx = (i + lane < e) ? csr[i + lane] : 0;
        int m = e - i;
#pragma unroll
        for (int t = 0; t < 8; ++t) {
            if (t * 8 >= m) break;            // wave-uniform early exit
            int ei2 = t * 8 + g;
            int r = __shfl(idx, ei2);
            unsigned v = (ei2 < m && f < 6) ? xd8[r * 8 + f] : 0u;
            ax += bflo(v); ay += bfhi(v);
        }
    }
    ax += __shfl_xor(ax, 8);  ay += __shfl_xor(ay, 8);
    ax += __shfl_xor(ax, 16); ay += __shfl_xor(ay, 16);
    ax += __shfl_xor(ax, 32); ay += __shfl_xor(ay, 32);
    if (g == 0 && f < 6) {
        unsigned sv = xd8[node * 8 + f];          // self loop
        aggf2[node * 8 + f] = make_float2(ax + bflo(sv), ay + bfhi(sv));
    }
}

// ---- fused layer-1 transform + layer-2 matmul; LDS-staged coalesced y2 store ----
__global__ __launch_bounds__(256) void k_l1l2(const float2* __restrict__ aggf2,
                                              const float* __restrict__ W1,
                                              const float* __restrict__ b1,
                                              const unsigned* __restrict__ w2t,
                                              const float* __restrict__ dis,
                                              unsigned* __restrict__ yb) {
    __shared__ float w1s[NF * HID];        // 5.5 KB
    __shared__ float xs[64 * 16];          // 4 KB
    __shared__ unsigned h1s[64 * 64];      // 16 KB (h1 swizzled; later y2 staging)
    const int tid = threadIdx.x;
    const int n0 = blockIdx.x * 64;
    const int wid = tid >> 6, lane = tid & 63;
    const int lr = lane & 15, lk = lane >> 4;
    const int colb = wid * 32;

    for (int i = tid; i < NF * HID; i += 256) w1s[i] = W1[i];
#pragma unroll
    for (int p = 0; p < 2; ++p) {
        int idx = p * 256 + tid;
        int nl = idx >> 3, l = idx & 7;
        int n = n0 + nl;
        float2 v = make_float2(0.f, 0.f);
        if (l < 6 && n < NN) {
            double dv = __builtin_nontemporal_load((const double*)aggf2 + (size_t)n * 8 + l);
            union { double d; float2 f; } cv; cv.d = dv;
            v = cv.f;
        }
        xs[nl * 16 + 2 * l] = v.x;
        xs[nl * 16 + 2 * l + 1] = v.y;
    }
    const uint4* w4 = (const uint4*)w2t;
    bf16x8 Bf[2][4];
#pragma unroll
    for (int c = 0; c < 2; ++c)
#pragma unroll
        for (int ks = 0; ks < 4; ++ks)
            Bf[c][ks] = as_bf(w4[(colb + c * 16 + lr) * 16 + ks * 4 + lk]);
    __syncthreads();

    // phase 1: h1 = relu(dis*(agg@W1)+b1) -> swizzled LDS
    const int f2 = tid & 63, sub = tid >> 6;
    float2 bb = ((const float2*)b1)[f2];
    const int jsw = f2 >> 2, ci = f2 & 3;
#pragma unroll
    for (int p = 0; p < 16; ++p) {
        int nl = p * 4 + sub;
        int n = n0 + nl;
        float s0 = 0.f, s1 = 0.f;
#pragma unroll
        for (int k = 0; k < NF; ++k) {
            float xv = xs[nl * 16 + k];
            s0 = fmaf(xv, w1s[k * HID + f2 * 2], s0);
            s1 = fmaf(xv, w1s[k * HID + f2 * 2 + 1], s1);
        }
        float d = (n < NN) ? dis[n] : 0.f;
        float ax = fmaxf(fmaf(s0, d, bb.x), 0.f);
        float ay = fmaxf(fmaf(s1, d, bb.y), 0.f);
        h1s[nl * 64 + ((jsw ^ (nl & 15)) << 2) + ci] = packbf(ax, ay);
    }
    __syncthreads();

    // phase 2: MFMA from LDS
    const uint4* h4 = (const uint4*)h1s;
    f32x4 acc[4][2];
#pragma unroll
    for (int r = 0; r < 4; ++r)
#pragma unroll
        for (int c = 0; c < 2; ++c) {
            f32x4 z = {0.f, 0.f, 0.f, 0.f};
            acc[r][c] = z;
        }
#pragma unroll
    for (int ks = 0; ks < 4; ++ks) {
        bf16x8 Af[4];
#pragma unroll
        for (int r = 0; r < 4; ++r)
            Af[r] = as_bf(h4[(r * 16 + lr) * 16 + ((ks * 4 + lk) ^ lr)]);
#pragma unroll
        for (int r = 0; r < 4; ++r)
#pragma unroll
            for (int c = 0; c < 2; ++c)
                acc[r][c] = __builtin_amdgcn_mfma_f32_16x16x32_bf16(Af[r], Bf[c][ks], acc[r][c], 0, 0, 0);
    }
    __syncthreads();   // all h1s reads done; reuse as y2 staging

    // epilogue: scale, pack, scatter into LDS (bank-swizzled), then coalesced store
#pragma unroll
    for (int r = 0; r < 4; ++r) {
#pragma unroll
        for (int i = 0; i < 4; ++i) {
            int ndl = r * 16 + lk * 4 + i;
            int nd = n0 + ndl;
            float d = (nd < NN) ? dis[nd] : 0.f;
            int swz = ((r * 4 + lk) & 3) << 3;
#pragma unroll
            for (int c = 0; c < 2; ++c) {
                float v = acc[r][c][i] * d;
                float o = __shfl_xor(v, 1);
                if (!(lane & 1)) {
                    int cu = (colb >> 1) + c * 8 + (lr >> 1);
                    h1s[ndl * 64 + (cu ^ swz)] = packbf(v, o);
                }
            }
        }
    }
    __syncthreads();
    uint4* yb4 = (uint4*)yb;
    const uint4* h1s4 = (const uint4*)h1s;
#pragma unroll
    for (int it = 0; it < 4; ++it) {
        int idx4 = it * 256 + tid;            // uint4 index within 64x16 tile
        int ndl = idx4 >> 4, cu4 = (idx4 & 15) * 4;
        int s = (ndl >> 2) & 3;
        int nd = n0 + ndl;
        if (nd < NN)
            yb4[(size_t)nd * 16 + (idx4 & 15)] = h1s4[(ndl * 64 + (cu4 ^ (s << 3))) >> 2];
    }
}

// ---- gather layer 2 (64 lanes/node, 8-deep batches) ----
__global__ __launch_bounds__(256) void k_gather(const unsigned* __restrict__ yb,
                                                const int* __restrict__ startp,
                                                const int* __restrict__ csr_rows,
                                                const float* __restrict__ dis,
                                                const float* __restrict__ b,
                                                unsigned* __restrict__ hb) {
    const int node = blockIdx.x * 4 + (threadIdx.x >> 6);
    const int lane = threadIdx.x & 63;
    int s = __builtin_nontemporal_load(startp + node);
    int e = __builtin_nontemporal_load(startp + node + 1);
    unsigned sv = yb[node * 64 + lane];           // self loop
    float ax = bflo(sv), ay = bfhi(sv);
    for (int i = s; i < e; i += 64) {
        int idx = (i + lane < e) ? __builtin_nontemporal_load(csr_rows + i + lane) : 0;
        int m = min(64, e - i);
        int j = 0;
        for (; j + 7 < m; j += 8) {
            unsigned v[8];
#pragma unroll
            for (int u = 0; u < 8; ++u) {
                int r = __shfl(idx, j + u);
                v[u] = yb[r * 64 + lane];
            }
#pragma unroll
            for (int u = 0; u < 8; ++u) { ax += bflo(v[u]); ay += bfhi(v[u]); }
        }
        for (; j + 3 < m; j += 4) {
            unsigned v[4];
#pragma unroll
            for (int u = 0; u < 4; ++u) {
                int r = __shfl(idx, j + u);
                v[u] = yb[r * 64 + lane];
            }
#pragma unroll
            for (int u = 0; u < 4; ++u) { ax += bflo(v[u]); ay += bfhi(v[u]); }
        }
        for (; j < m; ++j) {
            int r = __shfl(idx, j);
            unsigned v = yb[r * 64 + lane];
            ax += bflo(v); ay += bfhi(v);
        }
    }
    float d = dis[node];
    float2 bb = ((const float2*)b)[lane];
    ax = fmaxf(fmaf(ax, d, bb.x), 0.f);
    ay = fmaxf(fmaf(ay, d, bb.y), 0.f);
    hb[node * 64 + lane] = packbf(ax, ay);
}

// ---- fused mean-pool + head: 16 graphs per 256-thr block ----
__global__ __launch_bounds__(256) void k_headp(const unsigned* __restrict__ hb, const int* __restrict__ gs,
                                               const float* __restrict__ Wl1, const float* __restrict__ bl1,
                                               const float* __restrict__ Wl2, const float* __restrict__ bl2,
                                               float* __restrict__ out) {
    __shared__ float wl[HID * HID];   // 64 KB
    __shared__ float p[2][HID];
    __shared__ float tmp[2][HID];
    __shared__ float red[4];
    const int tid = threadIdx.x;
    const int f = tid & 127, half = tid >> 7;
    const int w = tid >> 6, lane = tid & 63;
    for (int i = tid; i < HID * HID; i += 256) wl[i] = Wl1[i];
    const float w2f = Wl2[f];
    const float b1f = bl1[f];
    const float b2f = bl2[0];
    const int f2l = f & 63;        // feature pair
    const int nstr = f >> 6;       // node stride phase (0/1)
    const int g0 = blockIdx.x * 16;
    for (int gi = 0; gi < 16; gi += 2) {
        int g = g0 + gi + half;
        int s = gs[g], e = gs[g + 1];
        // pool this graph with 2 waves (node-strided)
        float ax = 0.f, ay = 0.f;
        for (int n = s + nstr; n < e; n += 2) {
            unsigned v = hb[(size_t)n * 64 + f2l];
            ax += bflo(v); ay += bfhi(v);
        }
        if (nstr) { tmp[half][2 * f2l] = ax; tmp[half][2 * f2l + 1] = ay; }
        __syncthreads();
        if (!nstr) {
            float inv = 1.0f / (float)max(e - s, 1);
            p[half][2 * f2l]     = (ax + tmp[half][2 * f2l]) * inv;
            p[half][2 * f2l + 1] = (ay + tmp[half][2 * f2l + 1]) * inv;
        }
        __syncthreads();
        // MLP head
        float sacc = b1f;
#pragma unroll 16
        for (int k = 0; k < HID; ++k) sacc = fmaf(p[half][k], wl[k * HID + f], sacc);
        sacc = fmaxf(sacc, 0.f) * w2f;
#pragma unroll
        for (int off = 1; off < 64; off <<= 1) sacc += __shfl_xor(sacc, off);
        if (lane == 0) red[w] = sacc;
        __syncthreads();
        if (tid < 2) out[g0 + gi + tid] = red[tid * 2] + red[tid * 2 + 1] + b2f;
        __syncthreads();
    }
}

extern "C" void kernel_launch(void* const* d_in, const int* in_sizes, int n_in,
                              void* d_out, int out_size, void* d_ws, size_t ws_size,
                              hipStream_t stream) {
    const float* x   = (const float*)d_in[0];
    const float* W1  = (const float*)d_in[1];
    const float* b1  = (const float*)d_in[2];
    const float* W2  = (const float*)d_in[3];
    const float* b2  = (const float*)d_in[4];
    const float* Wl1 = (const float*)d_in[5];
    const float* bl1 = (const float*)d_in[6];
    const float* Wl2 = (const float*)d_in[7];
    const float* bl2 = (const float*)d_in[8];
    const int* ei    = (const int*)d_in[9];     // [2][NE]
    const int* batch = (const int*)d_in[10];
    float* out = (float*)d_out;

    const int* row = ei;
    const int* col = ei + NE;

    // workspace layout
    char* ws = (char*)d_ws;
    size_t off = 0;
    unsigned* yb   = (unsigned*)(ws + off); off += (size_t)NN * 64 * 4;   // 25.6 MB (y2)
    unsigned* hb   = (unsigned*)(ws + off); off += (size_t)NN * 64 * 4;   // 25.6 MB (h2; staging aliases)
    unsigned* xd8  = (unsigned*)(ws + off); off += (size_t)NN * 8 * 4;    // 3.2 MB
    float2* aggf2  = (float2*)  (ws + off); off += (size_t)NN * 8 * 8;    // 6.4 MB
    float* dis     = (float*)(ws + off); off += (size_t)NN * 4;
    int*   startp  = (int*)  (ws + off); off += (size_t)(NN + 1) * 4;
    int*   partial = (int*)  (ws + off); off += 1024 * 4;
    int*   csr     = (int*)  (ws + off); off += (size_t)NE * 4;           // 6.4 MB
    int*   gs      = (int*)  (ws + off); off += (size_t)(NG + 1) * 4;
    int*   bcur    = (int*)  (ws + off); off += (size_t)NBK * 4;
    unsigned* w2t  = (unsigned*)(ws + off); off += (size_t)HID * 64 * 4;  // 32 KB
    int*   staging = (int*)hb;   // aliases hb: hb first written by k_gather, after CSR build

    // ---- CSR build + misc (xd fused into hist2s) ----
    k_misc<<<32, 256, 0, stream>>>(bcur, W2, w2t, batch, gs, startp);
    k_bucket<<<NBB, 256, 0, stream>>>(row, col, bcur, staging);
    k_hist2s<<<NBK, 256, 0, stream>>>(staging, bcur, x, dis, xd8, startp, partial);
    k_scan2<<<1, 1024, 0, stream>>>(partial);
    k_fillbs<<<NBK, 256, 0, stream>>>(staging, bcur, partial, startp, csr);

    // ---- layer 1 (aggregate-then-transform) fused into layer-2 matmul ----
    k_gat1<<<NN / 4, 256, 0, stream>>>(xd8, startp, csr, aggf2);
    k_l1l2<<<(NN + 63) / 64, 256, 0, stream>>>(aggf2, W1, b1, w2t, dis, yb);

    // ---- layer 2 gather ----
    k_gather<<<NN / 4, 256, 0, stream>>>(yb, startp, csr, dis, b2, hb);

    // ---- fused pool + head ----
    k_headp<<<NG / 16, 256, 0, stream>>>(hb, gs, Wl1, bl1, Wl2, bl2, out);
}

// Round 13
// 206.056 us; speedup vs baseline: 1.1233x; 1.1233x over previous
//
#include <hip/hip_runtime.h>

#define NN 100000      // nodes
#define NE 1600000     // edges (without self loops)
#define NF 11          // input features
#define HID 128
#define NG 4096        // graphs

#define BSH 7
#define BNODES 128     // nodes per bucket = 1<<BSH
#define NBK 782        // ceil(NN/BNODES)
#define CAP 3072       // staging capacity per bucket (avg 2046)
#define EPB 4096       // edges per k_bucket block
#define NBB 391        // ceil(NE/EPB)

typedef short bf16x8 __attribute__((ext_vector_type(8)));
typedef float f32x4 __attribute__((ext_vector_type(4)));

// ---- bf16 pack/unpack helpers (RNE, no-NaN data) ----
__device__ __forceinline__ unsigned short f2bf(float f) {
    unsigned u = __float_as_uint(f);
    return (unsigned short)((u + 0x7FFFu + ((u >> 16) & 1u)) >> 16);
}
__device__ __forceinline__ unsigned packbf(float a, float b) {
    return (unsigned)f2bf(a) | ((unsigned)f2bf(b) << 16);
}
__device__ __forceinline__ float bflo(unsigned v) { return __uint_as_float(v << 16); }
__device__ __forceinline__ float bfhi(unsigned v) { return __uint_as_float(v & 0xFFFF0000u); }
__device__ __forceinline__ bf16x8 as_bf(uint4 u) { union { uint4 a; bf16x8 b; } v; v.a = u; return v.b; }

// ---- misc fused: zero bcur, pack W2 -> w2t, graph bounds, startp[NN]=NE ----
__global__ __launch_bounds__(256) void k_misc(int* __restrict__ bcur,
                                              const float* __restrict__ W2, unsigned* __restrict__ w2t,
                                              const int* __restrict__ batch, int* __restrict__ gs,
                                              int* __restrict__ startp) {
    int i = blockIdx.x * 256 + threadIdx.x;
    if (i < NBK) bcur[i] = 0;
    if (i < HID * 64) {   // 8192
        int col = i >> 6, kw = i & 63;
        w2t[col * 64 + kw] = packbf(W2[(2 * kw) * HID + col], W2[(2 * kw + 1) * HID + col]);
    }
    if (i <= NG) {
        int lo = 0, hi = NN;
        while (lo < hi) {
            int mid = (lo + hi) >> 1;
            if (batch[mid] < i) lo = mid + 1; else hi = mid;
        }
        gs[i] = lo;
    }
    if (i == 0) startp[NN] = NE;
}

// ---- pass 1: bucket edges by col>>7 into staging (workgroup multisplit) ----
__global__ __launch_bounds__(256) void k_bucket(const int* __restrict__ row, const int* __restrict__ col,
                                                int* __restrict__ bcur, int* __restrict__ staging) {
    __shared__ int cnt[NBK];
    __shared__ int loc[NBK];
    const int tid = threadIdx.x;
    const int e0 = blockIdx.x * EPB;
    for (int i = tid; i < NBK; i += 256) { cnt[i] = 0; loc[i] = 0; }
    __syncthreads();
    int rb[16]; unsigned pay[16];
#pragma unroll
    for (int j = 0; j < 16; ++j) {
        int e = e0 + j * 256 + tid;
        int c = (e < NE) ? col[e] : -1;
        int r = (e < NE) ? row[e] : 0;
        rb[j] = (c >= 0) ? (c >> BSH) : -1;
        pay[j] = (unsigned)r | ((unsigned)(c & (BNODES - 1)) << 17);
        if (rb[j] >= 0) atomicAdd(&cnt[rb[j]], 1);
    }
    __syncthreads();
    for (int b = tid; b < NBK; b += 256) {
        int c = cnt[b];
        cnt[b] = (c > 0) ? atomicAdd(&bcur[b], c) : 0;
    }
    __syncthreads();
#pragma unroll
    for (int j = 0; j < 16; ++j) {
        if (rb[j] >= 0) {
            int p = cnt[rb[j]] + atomicAdd(&loc[rb[j]], 1);
            staging[rb[j] * CAP + p] = (int)pay[j];
        }
    }
}

// ---- pass 2a: per-bucket histogram + local exclusive scan -> dis, startp(local), partial ----
__global__ __launch_bounds__(256) void k_hist2s(const int* __restrict__ staging, const int* __restrict__ bcur,
                                                float* __restrict__ dis, int* __restrict__ startp,
                                                int* __restrict__ partial) {
    __shared__ int cnt[BNODES];
    __shared__ int sc[BNODES];
    const int b = blockIdx.x, tid = threadIdx.x;
    if (tid < BNODES) cnt[tid] = 0;
    __syncthreads();
    const int sz = bcur[b];
    const int base = b * CAP;
    for (int i = tid; i < sz; i += 256)
        atomicAdd(&cnt[((unsigned)staging[base + i]) >> 17], 1);
    __syncthreads();
    int v = (tid < BNODES) ? cnt[tid] : 0;
    if (tid < BNODES) sc[tid] = v;
    __syncthreads();
    for (int off = 1; off < BNODES; off <<= 1) {
        int u = (tid < BNODES && tid >= off) ? sc[tid - off] : 0;
        __syncthreads();
        if (tid < BNODES) sc[tid] += u;
        __syncthreads();
    }
    int n = b * BNODES + tid;
    if (tid < BNODES && n < NN) {
        startp[n] = sc[tid] - v;               // bucket-local exclusive
        dis[n] = rsqrtf((float)(v + 1));
    }
    if (tid == BNODES - 1) partial[b] = sc[BNODES - 1];   // bucket total
}

// ---- scan bucket totals (1 block, 1024 thr) ----
__global__ __launch_bounds__(1024) void k_scan2(int* __restrict__ partial) {
    __shared__ int sh[1024];
    int t = threadIdx.x;
    int v = (t < NBK) ? partial[t] : 0;
    sh[t] = v; __syncthreads();
    for (int off = 1; off < 1024; off <<= 1) {
        int u = (t >= off) ? sh[t - off] : 0; __syncthreads();
        sh[t] += u; __syncthreads();
    }
    if (t < NBK) partial[t] = sh[t] - v;       // exclusive bucket base
}

// ---- pass 2b: finalize startp and counting-sort into CSR ----
__global__ __launch_bounds__(256) void k_fillbs(const int* __restrict__ staging, const int* __restrict__ bcur,
                                                const int* __restrict__ partial,
                                                int* __restrict__ startp, int* __restrict__ csr) {
    __shared__ int cur[BNODES];
    const int b = blockIdx.x, tid = threadIdx.x;
    const int bb = partial[b];
    int n = b * BNODES + tid;
    if (tid < BNODES) {
        int sfin = 0;
        if (n < NN) {
            sfin = startp[n] + bb;
            startp[n] = sfin;
        }
        cur[tid] = sfin;
    }
    __syncthreads();
    const int sz = bcur[b];
    const int base = b * CAP;
    for (int i = tid; i < sz; i += 256) {
        unsigned p = (unsigned)staging[base + i];
        int pos = atomicAdd(&cur[p >> 17], 1);
        csr[pos] = (int)(p & 0x1FFFF);
    }
}

// ---- xd = bf16(dis[n] * x[n]) ; 11 feats -> 6 packed uints, row padded to 8 (32 B) ----
__global__ __launch_bounds__(256) void k_xd(const float* __restrict__ x, const float* __restrict__ dis,
                                            unsigned* __restrict__ xd8) {
    const int n = blockIdx.x * 16 + (threadIdx.x >> 4);
    const int lane = threadIdx.x & 15;
    float f = (lane < NF) ? x[(size_t)n * NF + lane] : 0.f;
    f *= dis[n];
    float g = __shfl_down(f, 1, 16);
    if ((lane & 1) == 0 && lane < NF)
        xd8[n * 8 + (lane >> 1)] = packbf(f, g);
}

// ---- gather layer 1 on 11-wide xd: one wave per node, 8 edge-groups x 8 feat-lanes ----
__global__ __launch_bounds__(256) void k_gat1(const unsigned* __restrict__ xd8,
                                              const int* __restrict__ startp,
                                              const int* __restrict__ csr,
                                              unsigned* __restrict__ aggb) {
    const int node = blockIdx.x * 4 + (threadIdx.x >> 6);
    const int lane = threadIdx.x & 63;
    const int g = lane >> 3, f = lane & 7;    // 8 groups of 8 feat-lanes
    const int s = startp[node], e = startp[node + 1];
    float ax = 0.f, ay = 0.f;
    for (int i = s; i < e; i += 64) {
        int idx = (i + lane < e) ? csr[i + lane] : 0;
        int m = e - i;
#pragma unroll
        for (int t = 0; t < 8; ++t) {
            if (t * 8 >= m) break;            // wave-uniform early exit
            int ei2 = t * 8 + g;
            int r = __shfl(idx, ei2);
            unsigned v = (ei2 < m && f < 6) ? xd8[r * 8 + f] : 0u;
            ax += bflo(v); ay += bfhi(v);
        }
    }
    ax += __shfl_xor(ax, 8);  ay += __shfl_xor(ay, 8);
    ax += __shfl_xor(ax, 16); ay += __shfl_xor(ay, 16);
    ax += __shfl_xor(ax, 32); ay += __shfl_xor(ay, 32);
    if (g == 0 && f < 6) {
        unsigned sv = xd8[node * 8 + f];          // self loop
        aggb[node * 8 + f] = packbf(ax + bflo(sv), ay + bfhi(sv));
    }
}

// ---- fused layer-1 transform + layer-2 matmul; LDS-staged coalesced y2 store ----
__global__ __launch_bounds__(256) void k_l1l2(const unsigned* __restrict__ aggb,
                                              const float* __restrict__ W1,
                                              const float* __restrict__ b1,
                                              const unsigned* __restrict__ w2t,
                                              const float* __restrict__ dis,
                                              unsigned* __restrict__ yb) {
    __shared__ float w1s[NF * HID];        // 5.5 KB
    __shared__ float xs[64 * 16];          // 4 KB
    __shared__ unsigned h1s[64 * 64];      // 16 KB (h1 swizzled; later y2 staging)
    const int tid = threadIdx.x;
    const int n0 = blockIdx.x * 64;
    const int wid = tid >> 6, lane = tid & 63;
    const int lr = lane & 15, lk = lane >> 4;
    const int colb = wid * 32;

    for (int i = tid; i < NF * HID; i += 256) w1s[i] = W1[i];
#pragma unroll
    for (int p = 0; p < 2; ++p) {
        int idx = p * 256 + tid;
        int nl = idx >> 3, l = idx & 7;
        int n = n0 + nl;
        unsigned u = (l < 6 && n < NN) ? aggb[(size_t)n * 8 + l] : 0u;
        xs[nl * 16 + 2 * l] = bflo(u);
        xs[nl * 16 + 2 * l + 1] = bfhi(u);
    }
    const uint4* w4 = (const uint4*)w2t;
    bf16x8 Bf[2][4];
#pragma unroll
    for (int c = 0; c < 2; ++c)
#pragma unroll
        for (int ks = 0; ks < 4; ++ks)
            Bf[c][ks] = as_bf(w4[(colb + c * 16 + lr) * 16 + ks * 4 + lk]);
    __syncthreads();

    // phase 1: h1 = relu(dis*(agg@W1)+b1) -> swizzled LDS
    const int f2 = tid & 63, sub = tid >> 6;
    float2 bb = ((const float2*)b1)[f2];
    const int jsw = f2 >> 2, ci = f2 & 3;
#pragma unroll
    for (int p = 0; p < 16; ++p) {
        int nl = p * 4 + sub;
        int n = n0 + nl;
        float s0 = 0.f, s1 = 0.f;
#pragma unroll
        for (int k = 0; k < NF; ++k) {
            float xv = xs[nl * 16 + k];
            s0 = fmaf(xv, w1s[k * HID + f2 * 2], s0);
            s1 = fmaf(xv, w1s[k * HID + f2 * 2 + 1], s1);
        }
        float d = (n < NN) ? dis[n] : 0.f;
        float ax = fmaxf(fmaf(s0, d, bb.x), 0.f);
        float ay = fmaxf(fmaf(s1, d, bb.y), 0.f);
        h1s[nl * 64 + ((jsw ^ (nl & 15)) << 2) + ci] = packbf(ax, ay);
    }
    __syncthreads();

    // phase 2: MFMA from LDS
    const uint4* h4 = (const uint4*)h1s;
    f32x4 acc[4][2];
#pragma unroll
    for (int r = 0; r < 4; ++r)
#pragma unroll
        for (int c = 0; c < 2; ++c) {
            f32x4 z = {0.f, 0.f, 0.f, 0.f};
            acc[r][c] = z;
        }
#pragma unroll
    for (int ks = 0; ks < 4; ++ks) {
        bf16x8 Af[4];
#pragma unroll
        for (int r = 0; r < 4; ++r)
            Af[r] = as_bf(h4[(r * 16 + lr) * 16 + ((ks * 4 + lk) ^ lr)]);
#pragma unroll
        for (int r = 0; r < 4; ++r)
#pragma unroll
            for (int c = 0; c < 2; ++c)
                acc[r][c] = __builtin_amdgcn_mfma_f32_16x16x32_bf16(Af[r], Bf[c][ks], acc[r][c], 0, 0, 0);
    }
    __syncthreads();   // all h1s reads done; reuse as y2 staging

    // epilogue: scale, pack, scatter into LDS (bank-swizzled), then coalesced store
#pragma unroll
    for (int r = 0; r < 4; ++r) {
#pragma unroll
        for (int i = 0; i < 4; ++i) {
            int ndl = r * 16 + lk * 4 + i;
            int nd = n0 + ndl;
            float d = (nd < NN) ? dis[nd] : 0.f;
            int swz = ((r * 4 + lk) & 3) << 3;
#pragma unroll
            for (int c = 0; c < 2; ++c) {
                float v = acc[r][c][i] * d;
                float o = __shfl_xor(v, 1);
                if (!(lane & 1)) {
                    int cu = (colb >> 1) + c * 8 + (lr >> 1);
                    h1s[ndl * 64 + (cu ^ swz)] = packbf(v, o);
                }
            }
        }
    }
    __syncthreads();
    uint4* yb4 = (uint4*)yb;
    const uint4* h1s4 = (const uint4*)h1s;
#pragma unroll
    for (int it = 0; it < 4; ++it) {
        int idx4 = it * 256 + tid;            // uint4 index within 64x16 tile
        int ndl = idx4 >> 4, cu4 = (idx4 & 15) * 4;
        int s = (ndl >> 2) & 3;
        int nd = n0 + ndl;
        if (nd < NN)
            yb4[(size_t)nd * 16 + (idx4 & 15)] = h1s4[(ndl * 64 + (cu4 ^ (s << 3))) >> 2];
    }
}

// ---- gather layer 2 (64 lanes/node, 8-deep batches) ----
__global__ __launch_bounds__(256) void k_gather(const unsigned* __restrict__ yb,
                                                const int* __restrict__ startp,
                                                const int* __restrict__ csr_rows,
                                                const float* __restrict__ dis,
                                                const float* __restrict__ b,
                                                unsigned* __restrict__ hb) {
    const int node = blockIdx.x * 4 + (threadIdx.x >> 6);
    const int lane = threadIdx.x & 63;
    int s = startp[node], e = startp[node + 1];
    unsigned sv = yb[node * 64 + lane];           // self loop
    float ax = bflo(sv), ay = bfhi(sv);
    for (int i = s; i < e; i += 64) {
        int idx = (i + lane < e) ? csr_rows[i + lane] : 0;
        int m = min(64, e - i);
        int j = 0;
        for (; j + 7 < m; j += 8) {
            unsigned v[8];
#pragma unroll
            for (int u = 0; u < 8; ++u) {
                int r = __shfl(idx, j + u);
                v[u] = yb[r * 64 + lane];
            }
#pragma unroll
            for (int u = 0; u < 8; ++u) { ax += bflo(v[u]); ay += bfhi(v[u]); }
        }
        for (; j + 3 < m; j += 4) {
            unsigned v[4];
#pragma unroll
            for (int u = 0; u < 4; ++u) {
                int r = __shfl(idx, j + u);
                v[u] = yb[r * 64 + lane];
            }
#pragma unroll
            for (int u = 0; u < 4; ++u) { ax += bflo(v[u]); ay += bfhi(v[u]); }
        }
        for (; j < m; ++j) {
            int r = __shfl(idx, j);
            unsigned v = yb[r * 64 + lane];
            ax += bflo(v); ay += bfhi(v);
        }
    }
    float d = dis[node];
    float2 bb = ((const float2*)b)[lane];
    ax = fmaxf(fmaf(ax, d, bb.x), 0.f);
    ay = fmaxf(fmaf(ay, d, bb.y), 0.f);
    hb[node * 64 + lane] = packbf(ax, ay);
}

// ---- mean pool: 4 waves per graph ----
__global__ __launch_bounds__(256) void k_pool(const unsigned* __restrict__ hb, const int* __restrict__ gs,
                                              float* __restrict__ pooled) {
    __shared__ float rx[4][64], ry[4][64];
    const int g = blockIdx.x;
    const int w = threadIdx.x >> 6, lane = threadIdx.x & 63;
    int s = gs[g], e = gs[g + 1];
    float ax = 0.f, ay = 0.f;
    for (int n = s + w; n < e; n += 4) {
        unsigned v = hb[(size_t)n * 64 + lane];
        ax += bflo(v); ay += bfhi(v);
    }
    rx[w][lane] = ax; ry[w][lane] = ay;
    __syncthreads();
    if (w == 0) {
        ax = rx[0][lane] + rx[1][lane] + rx[2][lane] + rx[3][lane];
        ay = ry[0][lane] + ry[1][lane] + ry[2][lane] + ry[3][lane];
        float inv = 1.0f / (float)max(e - s, 1);
        pooled[(size_t)g * HID + lane * 2] = ax * inv;
        pooled[(size_t)g * HID + lane * 2 + 1] = ay * inv;
    }
}

// ---- head: Wl1 in LDS, 16 graphs per 256-thr block (2 at a time) ----
__global__ __launch_bounds__(256) void k_head(const float* __restrict__ pooled,
                                              const float* __restrict__ Wl1, const float* __restrict__ bl1,
                                              const float* __restrict__ Wl2, const float* __restrict__ bl2,
                                              float* __restrict__ out) {
    __shared__ float wl[HID * HID];   // 64 KB
    __shared__ float p[2][HID];
    __shared__ float red[4];
    const int tid = threadIdx.x;
    const int f = tid & 127, half = tid >> 7;
    const int w = tid >> 6, lane = tid & 63;
    for (int i = tid; i < HID * HID; i += 256) wl[i] = Wl1[i];
    const float w2f = Wl2[f];
    const float b1f = bl1[f];
    const float b2f = bl2[0];
    const int g0 = blockIdx.x * 16;
    for (int gi = 0; gi < 16; gi += 2) {
        int g = g0 + gi + half;
        p[half][f] = pooled[(size_t)g * HID + f];
        __syncthreads();
        float s = b1f;
#pragma unroll 16
        for (int k = 0; k < HID; ++k) s = fmaf(p[half][k], wl[k * HID + f], s);
        s = fmaxf(s, 0.f) * w2f;
#pragma unroll
        for (int off = 1; off < 64; off <<= 1) s += __shfl_xor(s, off);
        if (lane == 0) red[w] = s;
        __syncthreads();
        if (tid < 2) out[g0 + gi + tid] = red[tid * 2] + red[tid * 2 + 1] + b2f;
        __syncthreads();
    }
}

extern "C" void kernel_launch(void* const* d_in, const int* in_sizes, int n_in,
                              void* d_out, int out_size, void* d_ws, size_t ws_size,
                              hipStream_t stream) {
    const float* x   = (const float*)d_in[0];
    const float* W1  = (const float*)d_in[1];
    const float* b1  = (const float*)d_in[2];
    const float* W2  = (const float*)d_in[3];
    const float* b2  = (const float*)d_in[4];
    const float* Wl1 = (const float*)d_in[5];
    const float* bl1 = (const float*)d_in[6];
    const float* Wl2 = (const float*)d_in[7];
    const float* bl2 = (const float*)d_in[8];
    const int* ei    = (const int*)d_in[9];     // [2][NE]
    const int* batch = (const int*)d_in[10];
    float* out = (float*)d_out;

    const int* row = ei;
    const int* col = ei + NE;

    // workspace layout
    char* ws = (char*)d_ws;
    size_t off = 0;
    unsigned* yb   = (unsigned*)(ws + off); off += (size_t)NN * 64 * 4;   // 25.6 MB (y2)
    unsigned* hb   = (unsigned*)(ws + off); off += (size_t)NN * 64 * 4;   // 25.6 MB (h2; staging aliases)
    unsigned* xd8  = (unsigned*)(ws + off); off += (size_t)NN * 8 * 4;    // 3.2 MB
    unsigned* aggb = (unsigned*)(ws + off); off += (size_t)NN * 8 * 4;    // 3.2 MB (bf16 agg)
    float* dis     = (float*)(ws + off); off += (size_t)NN * 4;
    int*   startp  = (int*)  (ws + off); off += (size_t)(NN + 1) * 4;
    int*   partial = (int*)  (ws + off); off += 1024 * 4;
    int*   csr     = (int*)  (ws + off); off += (size_t)NE * 4;           // 6.4 MB
    int*   gs      = (int*)  (ws + off); off += (size_t)(NG + 1) * 4;
    float* pooled  = (float*)(ws + off); off += (size_t)NG * HID * 4;     // 2 MB
    int*   bcur    = (int*)  (ws + off); off += (size_t)NBK * 4;
    unsigned* w2t  = (unsigned*)(ws + off); off += (size_t)HID * 64 * 4;  // 32 KB
    int*   staging = (int*)hb;   // aliases hb: hb first written by k_gather, after CSR build

    // ---- CSR build (4 kernels) + misc ----
    k_misc<<<32, 256, 0, stream>>>(bcur, W2, w2t, batch, gs, startp);
    k_bucket<<<NBB, 256, 0, stream>>>(row, col, bcur, staging);
    k_hist2s<<<NBK, 256, 0, stream>>>(staging, bcur, dis, startp, partial);
    k_scan2<<<1, 1024, 0, stream>>>(partial);
    k_fillbs<<<NBK, 256, 0, stream>>>(staging, bcur, partial, startp, csr);

    // ---- layer 1 (aggregate-then-transform) fused into layer-2 matmul ----
    k_xd<<<NN / 16, 256, 0, stream>>>(x, dis, xd8);
    k_gat1<<<NN / 4, 256, 0, stream>>>(xd8, startp, csr, aggb);
    k_l1l2<<<(NN + 63) / 64, 256, 0, stream>>>(aggb, W1, b1, w2t, dis, yb);

    // ---- layer 2 gather ----
    k_gather<<<NN / 4, 256, 0, stream>>>(yb, startp, csr, dis, b2, hb);

    // ---- pool + head ----
    k_pool<<<NG, 256, 0, stream>>>(hb, gs, pooled);
    k_head<<<NG / 16, 256, 0, stream>>>(pooled, Wl1, bl1, Wl2, bl2, out);
}